// Round 4
// baseline (250.190 us; speedup 1.0000x reference)
//
#include <hip/hip_runtime.h>
#include <hip/hip_bf16.h>

using bf16_t = __bf16;
using bf16x4 = __attribute__((ext_vector_type(4))) __bf16;
using bf16x8 = __attribute__((ext_vector_type(8))) __bf16;
using f32x4  = __attribute__((ext_vector_type(4))) float;
using u32 = unsigned int;

constexpr int S_ = 2048, E_ = 1024, M_ = 4096;
constexpr size_t MAT_A = (size_t)M_ * E_;
constexpr size_t MAT_W = (size_t)E_ * E_;

__device__ __forceinline__ bf16_t tobf(float f) {
  unsigned u = __builtin_bit_cast(unsigned, f);
  unsigned short r = (unsigned short)((u + 0x7fffu + ((u >> 16) & 1u)) >> 16);
  return __builtin_bit_cast(bf16_t, r);
}
__device__ __forceinline__ u32 packbf2(float a, float b) {
  u32 ua = __builtin_bit_cast(u32, a) + 0x8000u;
  u32 ub = __builtin_bit_cast(u32, b) + 0x8000u;
  return (ua >> 16) | (ub & 0xffff0000u);
}
__device__ __forceinline__ void async_lds16(const bf16_t* g, bf16_t* l) {
  __builtin_amdgcn_global_load_lds(
      (const __attribute__((address_space(1))) unsigned int*)g,
      (__attribute__((address_space(3))) unsigned int*)l, 16, 0, 0);
}

// ---------------------------------------------------------------------------
__global__ __launch_bounds__(256) void cvt4k(
    const float* __restrict__ s0, const float* __restrict__ s1,
    const float* __restrict__ s2, const float* __restrict__ s3,
    bf16_t* __restrict__ d0, bf16_t* __restrict__ d1,
    bf16_t* __restrict__ d2, bf16_t* __restrict__ d3) {
  const int w = blockIdx.y;
  const float* s = w == 0 ? s0 : w == 1 ? s1 : w == 2 ? s2 : s3;
  bf16_t* d = w == 0 ? d0 : w == 1 ? d1 : w == 2 ? d2 : d3;
  size_t i = ((size_t)blockIdx.x * 256 + threadIdx.x) * 8;
  float4 a = *(const float4*)(s + i);
  float4 b = *(const float4*)(s + i + 4);
  bf16x8 o;
  o[0] = tobf(a.x); o[1] = tobf(a.y); o[2] = tobf(a.z); o[3] = tobf(a.w);
  o[4] = tobf(b.x); o[5] = tobf(b.y); o[6] = tobf(b.z); o[7] = tobf(b.w);
  *(bf16x8*)(d + i) = o;
}

// ---------------------------------------------------------------------------
// Fused QKV projection, 128x128 tile, BK=32, m97 staging. which = y>>3.
// V blocks write transposed Vt[bh][d][tok] directly (fused transpose).
// ---------------------------------------------------------------------------
__global__ __launch_bounds__(256) void gemm_qkv(
    const bf16_t* __restrict__ xq, const bf16_t* __restrict__ xk,
    const bf16_t* __restrict__ xv, const bf16_t* __restrict__ wq,
    const bf16_t* __restrict__ wk, const bf16_t* __restrict__ wv,
    const float* __restrict__ bq, const float* __restrict__ bk,
    const float* __restrict__ bv, bf16_t* __restrict__ outb,
    bf16_t* __restrict__ Vt) {
  constexpr int K = 1024, N = 1024, BK = 32;
  __shared__ __align__(16) bf16_t As[128 * BK];
  __shared__ __align__(16) bf16_t Bs[128 * BK];
  const int which = blockIdx.y >> 3;
  const bf16_t* X = which == 0 ? xq : which == 1 ? xk : xv;
  const bf16_t* W = which == 0 ? wq : which == 1 ? wk : wv;
  const float* bias = which == 0 ? bq : which == 1 ? bk : bv;
  const int row0 = blockIdx.x * 128, col0 = (blockIdx.y & 7) * 128;

  const int tid = threadIdx.x, lane = tid & 63, wave = tid >> 6;
  const int l15 = lane & 15, q = lane >> 4;
  const int wm = (wave & 1) * 64, wn = (wave >> 1) * 64;
  const f32x4 fzero = {0.f, 0.f, 0.f, 0.f};

  f32x4 acc[4][4];
#pragma unroll
  for (int i = 0; i < 4; ++i)
#pragma unroll
    for (int j = 0; j < 4; ++j) acc[i][j] = fzero;

  const bf16_t* gA = X + (size_t)(row0 + wave * 32 + (lane >> 2)) * K + (lane & 3) * 8;
  const bf16_t* gB = W + (size_t)(col0 + wave * 32 + (lane >> 2)) * K + (lane & 3) * 8;
  bf16_t* lA = As + wave * 32 * BK;
  bf16_t* lB = Bs + wave * 32 * BK;

  for (int k0 = 0; k0 < K; k0 += BK) {
    __syncthreads();
    async_lds16(gA + k0, lA);
    async_lds16(gA + k0 + 16 * K, lA + 16 * BK);
    async_lds16(gB + k0, lB);
    async_lds16(gB + k0 + 16 * K, lB + 16 * BK);
    __syncthreads();
    bf16x8 af[4], bw[4];
#pragma unroll
    for (int i = 0; i < 4; ++i)
      af[i] = *(const bf16x8*)(As + (wm + i * 16 + l15) * BK + q * 8);
#pragma unroll
    for (int j = 0; j < 4; ++j)
      bw[j] = *(const bf16x8*)(Bs + (wn + j * 16 + l15) * BK + q * 8);
#pragma unroll
    for (int i = 0; i < 4; ++i)
#pragma unroll
      for (int j = 0; j < 4; ++j)
        acc[i][j] = __builtin_amdgcn_mfma_f32_16x16x32_bf16(af[i], bw[j],
                                                            acc[i][j], 0, 0, 0);
  }

  if (which < 2) {
    bf16_t* C = outb + (size_t)which * MAT_A;
#pragma unroll
    for (int j = 0; j < 4; ++j) {
      const int col = col0 + wn + j * 16 + l15;
      const float bc = bias[col];
#pragma unroll
      for (int i = 0; i < 4; ++i)
#pragma unroll
        for (int r = 0; r < 4; ++r) {
          const int row = row0 + wm + i * 16 + q * 4 + r;
          C[(size_t)row * N + col] = tobf(acc[i][j][r] + bc);
        }
    }
  } else {
    // transposed write: Vt[(b*16+head)*64 + d][tok], 4 consecutive toks/lane
#pragma unroll
    for (int j = 0; j < 4; ++j) {
      const int col = col0 + wn + j * 16 + l15;
      const float bc = bias[col];
      const int head = col >> 6, d = col & 63;
#pragma unroll
      for (int i = 0; i < 4; ++i) {
        const int row = row0 + wm + i * 16 + q * 4;
        const int bb = row >> 11, tok = row & 2047;
        bf16x4 o;
#pragma unroll
        for (int r = 0; r < 4; ++r) o[r] = tobf(acc[i][j][r] + bc);
        *(bf16x4*)(Vt + ((size_t)(bb * 16 + head) * 64 + d) * S_ + tok) = o;
      }
    }
  }
}

// ---------------------------------------------------------------------------
// O-projection: 64x128 tile (512 blocks, 2/CU), fp32 output + bias.
// ---------------------------------------------------------------------------
__global__ __launch_bounds__(256) void gemm_o(const bf16_t* __restrict__ X,
                                              const bf16_t* __restrict__ W,
                                              const float* __restrict__ bias,
                                              float* __restrict__ C) {
  constexpr int K = 1024, N = 1024, BK = 32;
  __shared__ __align__(16) bf16_t As[64 * BK];
  __shared__ __align__(16) bf16_t Bs[128 * BK];
  const int tid = threadIdx.x, lane = tid & 63, wave = tid >> 6;
  const int l15 = lane & 15, q = lane >> 4;
  const int row0 = blockIdx.x * 64, col0 = blockIdx.y * 128;
  const int wm = (wave & 1) * 32, wn = (wave >> 1) * 64;
  const f32x4 fzero = {0.f, 0.f, 0.f, 0.f};

  f32x4 acc[2][4];
#pragma unroll
  for (int i = 0; i < 2; ++i)
#pragma unroll
    for (int j = 0; j < 4; ++j) acc[i][j] = fzero;

  const bf16_t* gA = X + (size_t)(row0 + wave * 16 + (lane >> 2)) * K + (lane & 3) * 8;
  const bf16_t* gB = W + (size_t)(col0 + wave * 32 + (lane >> 2)) * K + (lane & 3) * 8;
  bf16_t* lA = As + wave * 16 * BK;
  bf16_t* lB = Bs + wave * 32 * BK;

  for (int k0 = 0; k0 < K; k0 += BK) {
    __syncthreads();
    async_lds16(gA + k0, lA);
    async_lds16(gB + k0, lB);
    async_lds16(gB + k0 + 16 * K, lB + 16 * BK);
    __syncthreads();
    bf16x8 af[2], bw[4];
#pragma unroll
    for (int i = 0; i < 2; ++i)
      af[i] = *(const bf16x8*)(As + (wm + i * 16 + l15) * BK + q * 8);
#pragma unroll
    for (int j = 0; j < 4; ++j)
      bw[j] = *(const bf16x8*)(Bs + (wn + j * 16 + l15) * BK + q * 8);
#pragma unroll
    for (int i = 0; i < 2; ++i)
#pragma unroll
      for (int j = 0; j < 4; ++j)
        acc[i][j] = __builtin_amdgcn_mfma_f32_16x16x32_bf16(af[i], bw[j],
                                                            acc[i][j], 0, 0, 0);
  }

#pragma unroll
  for (int j = 0; j < 4; ++j) {
    const int col = col0 + wn + j * 16 + l15;
    const float bc = bias[col];
#pragma unroll
    for (int i = 0; i < 2; ++i)
#pragma unroll
      for (int r = 0; r < 4; ++r) {
        const int row = row0 + wm + i * 16 + q * 4 + r;
        C[(size_t)row * N + col] = acc[i][j][r] + bc;
      }
  }
}

// ---------------------------------------------------------------------------
// Flash attention, fixed-max softmax (partials exactly additive).
// Block = 4 waves, 64 Q-rows. Wave (wr, kh): rows [wr*32, wr*32+32),
// KV half kh (1024 toks, 16 tiles of 64). End: kh=1 partials merged via LDS.
// grid = 1024: bh = id&31 (same-XCD co-location), qb = id>>5.
// ---------------------------------------------------------------------------
__global__ __launch_bounds__(256) void attn_mfma(
    const bf16_t* __restrict__ Qm, const bf16_t* __restrict__ Km,
    const bf16_t* __restrict__ Vtg, bf16_t* __restrict__ Om) {
  constexpr int LDP = 72;
  __shared__ __align__(16) bf16_t Ks[2][64 * 64];
  __shared__ __align__(16) bf16_t Vs[2][64 * 64];
  __shared__ __align__(16) bf16_t Ps[4][2][16 * LDP];

  const int tid = threadIdx.x, lane = tid & 63, wave = tid >> 6;
  const int l15 = lane & 15, q = lane >> 4;
  const int wr = wave & 1, kh = wave >> 1;
  const int bh = blockIdx.x & 31, qb = blockIdx.x >> 5;
  const int b = bh >> 4, h = bh & 15;
  const size_t rowbase = (size_t)b * S_;
  const int hcol = h * 64;
  const int q0 = qb * 64 + wr * 32;
  constexpr float SC = 0.18033688011f;  // (1/8) * log2(e)

  // staging: wave covers rows [wr*32, wr*32+32) of its half's K and V tiles
  const int srow = lane >> 3;            // 0..7
  const int schunk = (lane & 7) ^ srow;  // xor chunk swizzle (read key = row&7)
  const bf16_t* gK = Km + (rowbase + kh * 1024 + wr * 32 + srow) * E_ + hcol + schunk * 8;
  const bf16_t* gV = Vtg + ((size_t)bh * 64 + wr * 32 + srow) * S_ + kh * 1024 + schunk * 8;
  bf16_t* lK = Ks[kh] + wr * 32 * 64;
  bf16_t* lV = Vs[kh] + wr * 32 * 64;

  // Q B-frags resident all loop
  bf16x8 qf[2][2];
#pragma unroll
  for (int qt = 0; qt < 2; ++qt) {
    const bf16_t* qp = Qm + (rowbase + q0 + qt * 16 + l15) * E_ + hcol + q * 8;
    qf[qt][0] = *(const bf16x8*)qp;
    qf[qt][1] = *(const bf16x8*)(qp + 32);
  }

  const f32x4 fzero = {0.f, 0.f, 0.f, 0.f};
  f32x4 oacc[2][4];
#pragma unroll
  for (int qt = 0; qt < 2; ++qt)
#pragma unroll
    for (int mt = 0; mt < 4; ++mt) oacc[qt][mt] = fzero;
  float lsum[2] = {0.f, 0.f};

  const int rbase = l15 * 64;
  int ck[2];
  ck[0] = ((q) ^ (l15 & 7)) * 8;
  ck[1] = ((4 + q) ^ (l15 & 7)) * 8;
  bf16_t* pw0 = Ps[wave][0] + l15 * LDP;
  bf16_t* pw1 = Ps[wave][1] + l15 * LDP;
  const bf16_t* Kbuf = Ks[kh];
  const bf16_t* Vbuf = Vs[kh];

  for (int t = 0; t < 16; ++t) {
    __syncthreads();
#pragma unroll
    for (int j = 0; j < 4; ++j) {
      async_lds16(gK + (size_t)(t * 64 + j * 8) * E_, lK + j * 512);
      async_lds16(gV + t * 64 + (size_t)(j * 8) * S_, lV + j * 512);
    }
    __syncthreads();

    // S^T = K Q^T ; p = exp2(s*SC); pack pairs -> LDS (B-layout for PV)
#pragma unroll
    for (int nt = 0; nt < 4; ++nt) {
      bf16x8 a0 = *(const bf16x8*)(Kbuf + nt * 1024 + rbase + ck[0]);
      bf16x8 a1 = *(const bf16x8*)(Kbuf + nt * 1024 + rbase + ck[1]);
#pragma unroll
      for (int qt = 0; qt < 2; ++qt) {
        f32x4 st = fzero;
        st = __builtin_amdgcn_mfma_f32_16x16x32_bf16(a0, qf[qt][0], st, 0, 0, 0);
        st = __builtin_amdgcn_mfma_f32_16x16x32_bf16(a1, qf[qt][1], st, 0, 0, 0);
        float p0 = __builtin_amdgcn_exp2f(st[0] * SC);
        float p1 = __builtin_amdgcn_exp2f(st[1] * SC);
        float p2 = __builtin_amdgcn_exp2f(st[2] * SC);
        float p3 = __builtin_amdgcn_exp2f(st[3] * SC);
        lsum[qt] += (p0 + p1) + (p2 + p3);
        uint2 pk;
        pk.x = packbf2(p0, p1);
        pk.y = packbf2(p2, p3);
        *(uint2*)((qt ? pw1 : pw0) + nt * 16 + q * 4) = pk;
      }
    }

    // O^T += V^T P^T
#pragma unroll
    for (int kk = 0; kk < 2; ++kk) {
      bf16x8 bp0 = *(const bf16x8*)(pw0 + kk * 32 + q * 8);
      bf16x8 bp1 = *(const bf16x8*)(pw1 + kk * 32 + q * 8);
#pragma unroll
      for (int mt = 0; mt < 4; ++mt) {
        bf16x8 av = *(const bf16x8*)(Vbuf + mt * 1024 + rbase + ck[kk]);
        oacc[0][mt] = __builtin_amdgcn_mfma_f32_16x16x32_bf16(av, bp0,
                                                              oacc[0][mt], 0, 0, 0);
        oacc[1][mt] = __builtin_amdgcn_mfma_f32_16x16x32_bf16(av, bp1,
                                                              oacc[1][mt], 0, 0, 0);
      }
    }
  }

  // merge kh=1 partials into kh=0 (exact: fixed-max partials are additive)
  __syncthreads();
  if (kh == 1) {
    float* dst = (float*)(wr == 0 ? Ks[0] : Vs[0]);  // 8 KB each, fits exactly
#pragma unroll
    for (int qt = 0; qt < 2; ++qt)
#pragma unroll
      for (int mt = 0; mt < 4; ++mt)
        *(f32x4*)(dst + ((qt * 4 + mt) * 64 + lane) * 4) = oacc[qt][mt];
    float* lf = (float*)Ps[wave];
    lf[lane] = lsum[0];
    lf[64 + lane] = lsum[1];
  }
  __syncthreads();
  if (kh == 0) {
    const float* src = (const float*)(wr == 0 ? Ks[0] : Vs[0]);
    const float* lf = (const float*)Ps[wave + 2];
#pragma unroll
    for (int qt = 0; qt < 2; ++qt) {
      float l = lsum[qt] + lf[qt * 64 + lane];
#pragma unroll
      for (int mt = 0; mt < 4; ++mt)
        oacc[qt][mt] += *(const f32x4*)(src + ((qt * 4 + mt) * 64 + lane) * 4);
      l += __shfl_xor(l, 16);
      l += __shfl_xor(l, 32);
      const float inv = 1.0f / l;
      const size_t orow = (rowbase + q0 + qt * 16 + l15) * E_ + hcol + q * 4;
#pragma unroll
      for (int mt = 0; mt < 4; ++mt) {
        bf16x4 o;
#pragma unroll
        for (int r = 0; r < 4; ++r) o[r] = tobf(oacc[qt][mt][r] * inv);
        *(bf16x4*)(Om + orow + mt * 16) = o;
      }
    }
  }
}

// ---------------------------------------------------------------------------
extern "C" void kernel_launch(void* const* d_in, const int* in_sizes, int n_in,
                              void* d_out, int out_size, void* d_ws, size_t ws_size,
                              hipStream_t stream) {
  const float* query = (const float*)d_in[0];
  const float* key_  = (const float*)d_in[1];
  const float* value = (const float*)d_in[2];
  const float* Wq = (const float*)d_in[3];
  const float* bq = (const float*)d_in[4];
  const float* Wk = (const float*)d_in[5];
  const float* bk = (const float*)d_in[6];
  const float* Wv = (const float*)d_in[7];
  const float* bv = (const float*)d_in[8];
  const float* Wo = (const float*)d_in[9];
  const float* bo = (const float*)d_in[10];

  bf16_t* qc  = (bf16_t*)d_ws;
  bf16_t* kc  = qc + MAT_A;
  bf16_t* vc  = kc + MAT_A;
  bf16_t* wqb = vc + MAT_A;
  bf16_t* wkb = wqb + MAT_W;
  bf16_t* wvb = wkb + MAT_W;
  bf16_t* wob = wvb + MAT_W;
  bf16_t* Qb  = wob + MAT_W;
  bf16_t* Kb  = Qb + MAT_A;
  bf16_t* Vt  = Kb + MAT_A;
  bf16_t* AOb = Vt + MAT_A;

  cvt4k<<<dim3(MAT_A / 2048, 3), 256, 0, stream>>>(query, key_, value, value,
                                                   qc, kc, vc, vc);
  cvt4k<<<dim3(MAT_W / 2048, 4), 256, 0, stream>>>(Wq, Wk, Wv, Wo,
                                                   wqb, wkb, wvb, wob);
  gemm_qkv<<<dim3(32, 24), 256, 0, stream>>>(qc, kc, vc, wqb, wkb, wvb,
                                             bq, bk, bv, Qb, Vt);
  attn_mfma<<<1024, 256, 0, stream>>>(Qb, Kb, Vt, AOb);
  gemm_o<<<dim3(64, 8), 256, 0, stream>>>(AOb, wob, bo, (float*)d_out);
}

// Round 5
// 238.938 us; speedup vs baseline: 1.0471x; 1.0471x over previous
//
#include <hip/hip_runtime.h>
#include <hip/hip_bf16.h>

using bf16_t = __bf16;
using bf16x4 = __attribute__((ext_vector_type(4))) __bf16;
using bf16x8 = __attribute__((ext_vector_type(8))) __bf16;
using f32x4  = __attribute__((ext_vector_type(4))) float;
using u32 = unsigned int;

constexpr int S_ = 2048, E_ = 1024, M_ = 4096;
constexpr size_t MAT_A = (size_t)M_ * E_;
constexpr size_t MAT_W = (size_t)E_ * E_;

__device__ __forceinline__ bf16_t tobf(float f) {
  unsigned u = __builtin_bit_cast(unsigned, f);
  unsigned short r = (unsigned short)((u + 0x7fffu + ((u >> 16) & 1u)) >> 16);
  return __builtin_bit_cast(bf16_t, r);
}
__device__ __forceinline__ u32 packbf2(float a, float b) {
  u32 ua = __builtin_bit_cast(u32, a) + 0x8000u;
  u32 ub = __builtin_bit_cast(u32, b) + 0x8000u;
  return (ua >> 16) | (ub & 0xffff0000u);
}
__device__ __forceinline__ void async_lds16(const bf16_t* g, bf16_t* l) {
  __builtin_amdgcn_global_load_lds(
      (const __attribute__((address_space(1))) unsigned int*)g,
      (__attribute__((address_space(3))) unsigned int*)l, 16, 0, 0);
}

// ---------------------------------------------------------------------------
// fp32 -> bf16, all 7 tensors in one launch. y = tensor id; 3 big (4M), 4 small.
// ---------------------------------------------------------------------------
__global__ __launch_bounds__(256) void cvt7(
    const float* __restrict__ s0, const float* __restrict__ s1,
    const float* __restrict__ s2, const float* __restrict__ s3,
    const float* __restrict__ s4, const float* __restrict__ s5,
    const float* __restrict__ s6,
    bf16_t* __restrict__ d0, bf16_t* __restrict__ d1,
    bf16_t* __restrict__ d2, bf16_t* __restrict__ d3,
    bf16_t* __restrict__ d4, bf16_t* __restrict__ d5,
    bf16_t* __restrict__ d6) {
  const int w = blockIdx.y;
  const size_t n = w < 3 ? MAT_A : MAT_W;
  size_t i = ((size_t)blockIdx.x * 256 + threadIdx.x) * 8;
  if (i >= n) return;
  const float* s = w == 0 ? s0 : w == 1 ? s1 : w == 2 ? s2 : w == 3 ? s3
                 : w == 4 ? s4 : w == 5 ? s5 : s6;
  bf16_t* d = w == 0 ? d0 : w == 1 ? d1 : w == 2 ? d2 : w == 3 ? d3
            : w == 4 ? d4 : w == 5 ? d5 : d6;
  float4 a = *(const float4*)(s + i);
  float4 b = *(const float4*)(s + i + 4);
  bf16x8 o;
  o[0] = tobf(a.x); o[1] = tobf(a.y); o[2] = tobf(a.z); o[3] = tobf(a.w);
  o[4] = tobf(b.x); o[5] = tobf(b.y); o[6] = tobf(b.z); o[7] = tobf(b.w);
  *(bf16x8*)(d + i) = o;
}

// ---------------------------------------------------------------------------
// Fused QKV projection, 128x128 tile, BK=32, m97 staging. which = y>>3.
// Q output pre-scaled by (1/8)*log2(e)  (folds softmax scale into projection;
// bf16 quantization error identical to scaling later).
// V blocks write transposed Vt[bh][d][tok] directly (fused transpose).
// ---------------------------------------------------------------------------
__global__ __launch_bounds__(256) void gemm_qkv(
    const bf16_t* __restrict__ xq, const bf16_t* __restrict__ xk,
    const bf16_t* __restrict__ xv, const bf16_t* __restrict__ wq,
    const bf16_t* __restrict__ wk, const bf16_t* __restrict__ wv,
    const float* __restrict__ bq, const float* __restrict__ bk,
    const float* __restrict__ bv, bf16_t* __restrict__ outb,
    bf16_t* __restrict__ Vt) {
  constexpr int K = 1024, N = 1024, BK = 32;
  constexpr float SC = 0.18033688011f;  // (1/8) * log2(e)
  __shared__ __align__(16) bf16_t As[128 * BK];
  __shared__ __align__(16) bf16_t Bs[128 * BK];
  const int which = blockIdx.y >> 3;
  const bf16_t* X = which == 0 ? xq : which == 1 ? xk : xv;
  const bf16_t* W = which == 0 ? wq : which == 1 ? wk : wv;
  const float* bias = which == 0 ? bq : which == 1 ? bk : bv;
  const int row0 = blockIdx.x * 128, col0 = (blockIdx.y & 7) * 128;

  const int tid = threadIdx.x, lane = tid & 63, wave = tid >> 6;
  const int l15 = lane & 15, q = lane >> 4;
  const int wm = (wave & 1) * 64, wn = (wave >> 1) * 64;
  const f32x4 fzero = {0.f, 0.f, 0.f, 0.f};

  f32x4 acc[4][4];
#pragma unroll
  for (int i = 0; i < 4; ++i)
#pragma unroll
    for (int j = 0; j < 4; ++j) acc[i][j] = fzero;

  const bf16_t* gA = X + (size_t)(row0 + wave * 32 + (lane >> 2)) * K + (lane & 3) * 8;
  const bf16_t* gB = W + (size_t)(col0 + wave * 32 + (lane >> 2)) * K + (lane & 3) * 8;
  bf16_t* lA = As + wave * 32 * BK;
  bf16_t* lB = Bs + wave * 32 * BK;

  for (int k0 = 0; k0 < K; k0 += BK) {
    __syncthreads();
    async_lds16(gA + k0, lA);
    async_lds16(gA + k0 + 16 * K, lA + 16 * BK);
    async_lds16(gB + k0, lB);
    async_lds16(gB + k0 + 16 * K, lB + 16 * BK);
    __syncthreads();
    bf16x8 af[4], bw[4];
#pragma unroll
    for (int i = 0; i < 4; ++i)
      af[i] = *(const bf16x8*)(As + (wm + i * 16 + l15) * BK + q * 8);
#pragma unroll
    for (int j = 0; j < 4; ++j)
      bw[j] = *(const bf16x8*)(Bs + (wn + j * 16 + l15) * BK + q * 8);
#pragma unroll
    for (int i = 0; i < 4; ++i)
#pragma unroll
      for (int j = 0; j < 4; ++j)
        acc[i][j] = __builtin_amdgcn_mfma_f32_16x16x32_bf16(af[i], bw[j],
                                                            acc[i][j], 0, 0, 0);
  }

  if (which < 2) {
    const float sc = which == 0 ? SC : 1.0f;
    bf16_t* C = outb + (size_t)which * MAT_A;
#pragma unroll
    for (int j = 0; j < 4; ++j) {
      const int col = col0 + wn + j * 16 + l15;
      const float bc = bias[col];
#pragma unroll
      for (int i = 0; i < 4; ++i)
#pragma unroll
        for (int r = 0; r < 4; ++r) {
          const int row = row0 + wm + i * 16 + q * 4 + r;
          C[(size_t)row * N + col] = tobf((acc[i][j][r] + bc) * sc);
        }
    }
  } else {
    // transposed write: Vt[(b*16+head)*64 + d][tok]
#pragma unroll
    for (int j = 0; j < 4; ++j) {
      const int col = col0 + wn + j * 16 + l15;
      const float bc = bias[col];
      const int head = col >> 6, d = col & 63;
#pragma unroll
      for (int i = 0; i < 4; ++i) {
        const int row = row0 + wm + i * 16 + q * 4;
        const int bb = row >> 11, tok = row & 2047;
        bf16x4 o;
#pragma unroll
        for (int r = 0; r < 4; ++r) o[r] = tobf(acc[i][j][r] + bc);
        *(bf16x4*)(Vt + ((size_t)(bb * 16 + head) * 64 + d) * S_ + tok) = o;
      }
    }
  }
}

// ---------------------------------------------------------------------------
// O-projection: 64x128 tile (512 blocks, 2/CU), fp32 output + bias.
// ---------------------------------------------------------------------------
__global__ __launch_bounds__(256) void gemm_o(const bf16_t* __restrict__ X,
                                              const bf16_t* __restrict__ W,
                                              const float* __restrict__ bias,
                                              float* __restrict__ C) {
  constexpr int K = 1024, N = 1024, BK = 32;
  __shared__ __align__(16) bf16_t As[64 * BK];
  __shared__ __align__(16) bf16_t Bs[128 * BK];
  const int tid = threadIdx.x, lane = tid & 63, wave = tid >> 6;
  const int l15 = lane & 15, q = lane >> 4;
  const int row0 = blockIdx.x * 64, col0 = blockIdx.y * 128;
  const int wm = (wave & 1) * 32, wn = (wave >> 1) * 64;
  const f32x4 fzero = {0.f, 0.f, 0.f, 0.f};

  f32x4 acc[2][4];
#pragma unroll
  for (int i = 0; i < 2; ++i)
#pragma unroll
    for (int j = 0; j < 4; ++j) acc[i][j] = fzero;

  const bf16_t* gA = X + (size_t)(row0 + wave * 16 + (lane >> 2)) * K + (lane & 3) * 8;
  const bf16_t* gB = W + (size_t)(col0 + wave * 32 + (lane >> 2)) * K + (lane & 3) * 8;
  bf16_t* lA = As + wave * 16 * BK;
  bf16_t* lB = Bs + wave * 32 * BK;

  for (int k0 = 0; k0 < K; k0 += BK) {
    __syncthreads();
    async_lds16(gA + k0, lA);
    async_lds16(gB + k0, lB);
    async_lds16(gB + k0 + 16 * K, lB + 16 * BK);
    __syncthreads();
    bf16x8 af[2], bw[4];
#pragma unroll
    for (int i = 0; i < 2; ++i)
      af[i] = *(const bf16x8*)(As + (wm + i * 16 + l15) * BK + q * 8);
#pragma unroll
    for (int j = 0; j < 4; ++j)
      bw[j] = *(const bf16x8*)(Bs + (wn + j * 16 + l15) * BK + q * 8);
#pragma unroll
    for (int i = 0; i < 2; ++i)
#pragma unroll
      for (int j = 0; j < 4; ++j)
        acc[i][j] = __builtin_amdgcn_mfma_f32_16x16x32_bf16(af[i], bw[j],
                                                            acc[i][j], 0, 0, 0);
  }

#pragma unroll
  for (int j = 0; j < 4; ++j) {
    const int col = col0 + wn + j * 16 + l15;
    const float bc = bias[col];
#pragma unroll
    for (int i = 0; i < 2; ++i)
#pragma unroll
      for (int r = 0; r < 4; ++r) {
        const int row = row0 + wm + i * 16 + q * 4 + r;
        C[(size_t)row * N + col] = acc[i][j][r] + bc;
      }
  }
}

// ---------------------------------------------------------------------------
// Flash attention, fixed-max softmax, Q pre-scaled (no per-score mul).
// Block = 4 waves × 32 Q-rows = 128 rows; all waves share one KV tile,
// double-buffered async staging -> ONE barrier per tile (stage(t+1) is
// issued after the barrier that consumed stage(t), so the vmcnt drain at
// each barrier waits on loads that had a full tile of compute to land).
// grid = 512: bh = id&31 (same-XCD under %8 round-robin), qb = id>>5.
// ---------------------------------------------------------------------------
__global__ __launch_bounds__(256) void attn_mfma(
    const bf16_t* __restrict__ Qm, const bf16_t* __restrict__ Km,
    const bf16_t* __restrict__ Vtg, bf16_t* __restrict__ Om) {
  constexpr int LDP = 72;
  __shared__ __align__(16) bf16_t Ks[2][64 * 64];
  __shared__ __align__(16) bf16_t Vs[2][64 * 64];
  __shared__ __align__(16) bf16_t Ps[4][2][16 * LDP];

  const int tid = threadIdx.x, lane = tid & 63, wave = tid >> 6;
  const int l15 = lane & 15, q = lane >> 4;
  const int bh = blockIdx.x & 31, qb = blockIdx.x >> 5;
  const int b = bh >> 4, h = bh & 15;
  const size_t rowbase = (size_t)b * S_;
  const int hcol = h * 64;
  const int q0 = qb * 128 + wave * 32;

  // staging: wave stages rows [wave*16, wave*16+16) of K tile and Vt tile.
  // xor chunk swizzle baked into fetch addr (read key = row&7).
  const int srow = lane >> 3;            // 0..7
  const int schunk = (lane & 7) ^ srow;  // fetched 16B chunk
  const bf16_t* gK = Km + (rowbase + wave * 16 + srow) * E_ + hcol + schunk * 8;
  const bf16_t* gV = Vtg + ((size_t)bh * 64 + wave * 16 + srow) * S_ + schunk * 8;

  // Q B-frags resident all loop (pre-scaled by SC in projection)
  bf16x8 qf[2][2];
#pragma unroll
  for (int qt = 0; qt < 2; ++qt) {
    const bf16_t* qp = Qm + (rowbase + q0 + qt * 16 + l15) * E_ + hcol + q * 8;
    qf[qt][0] = *(const bf16x8*)qp;
    qf[qt][1] = *(const bf16x8*)(qp + 32);
  }

  const f32x4 fzero = {0.f, 0.f, 0.f, 0.f};
  f32x4 oacc[2][4];
#pragma unroll
  for (int qt = 0; qt < 2; ++qt)
#pragma unroll
    for (int mt = 0; mt < 4; ++mt) oacc[qt][mt] = fzero;
  float lsum[2] = {0.f, 0.f};

  const int rbase = l15 * 64;
  int ck[2];
  ck[0] = ((q) ^ (l15 & 7)) * 8;
  ck[1] = ((4 + q) ^ (l15 & 7)) * 8;
  bf16_t* pw0 = Ps[wave][0] + l15 * LDP;
  bf16_t* pw1 = Ps[wave][1] + l15 * LDP;

  // prologue: stage tile 0 into buffer 0
  async_lds16(gK, Ks[0] + wave * 1024);
  async_lds16(gK + (size_t)8 * E_, Ks[0] + wave * 1024 + 512);
  async_lds16(gV, Vs[0] + wave * 1024);
  async_lds16(gV + (size_t)8 * S_, Vs[0] + wave * 1024 + 512);

  for (int t = 0; t < 32; ++t) {
    const int pb = t & 1;
    __syncthreads();  // stage(t) complete; all reads of buf pb^1 done
    if (t + 1 < 32) {
      const size_t koff = (size_t)((t + 1) * 64) * E_;
      const int voff = (t + 1) * 64;
      bf16_t* dK = Ks[pb ^ 1] + wave * 1024;
      bf16_t* dV = Vs[pb ^ 1] + wave * 1024;
      async_lds16(gK + koff, dK);
      async_lds16(gK + koff + (size_t)8 * E_, dK + 512);
      async_lds16(gV + voff, dV);
      async_lds16(gV + voff + (size_t)8 * S_, dV + 512);
    }
    const bf16_t* Kbuf = Ks[pb];
    const bf16_t* Vbuf = Vs[pb];

    // S^T = K Q^T ; p = exp2(s); pack pairs -> LDS (B-layout for PV)
#pragma unroll
    for (int nt = 0; nt < 4; ++nt) {
      bf16x8 a0 = *(const bf16x8*)(Kbuf + nt * 1024 + rbase + ck[0]);
      bf16x8 a1 = *(const bf16x8*)(Kbuf + nt * 1024 + rbase + ck[1]);
#pragma unroll
      for (int qt = 0; qt < 2; ++qt) {
        f32x4 st = fzero;
        st = __builtin_amdgcn_mfma_f32_16x16x32_bf16(a0, qf[qt][0], st, 0, 0, 0);
        st = __builtin_amdgcn_mfma_f32_16x16x32_bf16(a1, qf[qt][1], st, 0, 0, 0);
        float p0 = __builtin_amdgcn_exp2f(st[0]);
        float p1 = __builtin_amdgcn_exp2f(st[1]);
        float p2 = __builtin_amdgcn_exp2f(st[2]);
        float p3 = __builtin_amdgcn_exp2f(st[3]);
        lsum[qt] += (p0 + p1) + (p2 + p3);
        uint2 pk;
        pk.x = packbf2(p0, p1);
        pk.y = packbf2(p2, p3);
        *(uint2*)((qt ? pw1 : pw0) + nt * 16 + q * 4) = pk;
      }
    }

    // O^T += V^T P^T
#pragma unroll
    for (int kk = 0; kk < 2; ++kk) {
      bf16x8 bp0 = *(const bf16x8*)(pw0 + kk * 32 + q * 8);
      bf16x8 bp1 = *(const bf16x8*)(pw1 + kk * 32 + q * 8);
#pragma unroll
      for (int mt = 0; mt < 4; ++mt) {
        bf16x8 av = *(const bf16x8*)(Vbuf + mt * 1024 + rbase + ck[kk]);
        oacc[0][mt] = __builtin_amdgcn_mfma_f32_16x16x32_bf16(av, bp0,
                                                              oacc[0][mt], 0, 0, 0);
        oacc[1][mt] = __builtin_amdgcn_mfma_f32_16x16x32_bf16(av, bp1,
                                                              oacc[1][mt], 0, 0, 0);
      }
    }
  }

  // finalize per wave: reduce l across quads, normalize, store
#pragma unroll
  for (int qt = 0; qt < 2; ++qt) {
    float l = lsum[qt];
    l += __shfl_xor(l, 16);
    l += __shfl_xor(l, 32);
    const float inv = 1.0f / l;
    const size_t orow = (rowbase + q0 + qt * 16 + l15) * E_ + hcol + q * 4;
#pragma unroll
    for (int mt = 0; mt < 4; ++mt) {
      bf16x4 o;
#pragma unroll
      for (int r = 0; r < 4; ++r) o[r] = tobf(oacc[qt][mt][r] * inv);
      *(bf16x4*)(Om + orow + mt * 16) = o;
    }
  }
}

// ---------------------------------------------------------------------------
extern "C" void kernel_launch(void* const* d_in, const int* in_sizes, int n_in,
                              void* d_out, int out_size, void* d_ws, size_t ws_size,
                              hipStream_t stream) {
  const float* query = (const float*)d_in[0];
  const float* key_  = (const float*)d_in[1];
  const float* value = (const float*)d_in[2];
  const float* Wq = (const float*)d_in[3];
  const float* bq = (const float*)d_in[4];
  const float* Wk = (const float*)d_in[5];
  const float* bk = (const float*)d_in[6];
  const float* Wv = (const float*)d_in[7];
  const float* bv = (const float*)d_in[8];
  const float* Wo = (const float*)d_in[9];
  const float* bo = (const float*)d_in[10];

  bf16_t* qc  = (bf16_t*)d_ws;
  bf16_t* kc  = qc + MAT_A;
  bf16_t* vc  = kc + MAT_A;
  bf16_t* wqb = vc + MAT_A;
  bf16_t* wkb = wqb + MAT_W;
  bf16_t* wvb = wkb + MAT_W;
  bf16_t* wob = wvb + MAT_W;
  bf16_t* Qb  = wob + MAT_W;
  bf16_t* Kb  = Qb + MAT_A;
  bf16_t* Vt  = Kb + MAT_A;
  bf16_t* AOb = Vt + MAT_A;

  cvt7<<<dim3(MAT_A / 2048, 7), 256, 0, stream>>>(
      query, key_, value, Wq, Wk, Wv, Wo,
      qc, kc, vc, wqb, wkb, wvb, wob);
  gemm_qkv<<<dim3(32, 24), 256, 0, stream>>>(qc, kc, vc, wqb, wkb, wvb,
                                             bq, bk, bv, Qb, Vt);
  attn_mfma<<<512, 256, 0, stream>>>(Qb, Kb, Vt, AOb);
  gemm_o<<<dim3(64, 8), 256, 0, stream>>>(AOb, wob, bo, (float*)d_out);
}